// Round 12
// baseline (77.082 us; speedup 1.0000x reference)
//
#include <hip/hip_runtime.h>
#include <math.h>

// SparseMultiheadAttention B=2,H=16,S=2048,DH=64, STRIDE=128, EXPR=32, bidirectional.
// Mask factorization (HW-validated rounds 0-2):
//   allowed(i,c) = (c&127)>=96 | ((c&127)==0 && c>0) | ((c>>7)==a(i))
//   a(i) = (i>>7) - ((i&127)==0 && i>0)
// R12 = R11 + 2 row-tiles per wave (32 q-rows/wave, 128-row blocks, grid 512):
//   K/V LDS reads shared across the 2 tiles (1 kf -> 2 QK MFMAs, 1 vb -> 2 PV
//   MFMAs); device-wide barrier-interval count -45%; staging traffic halves.
// Kept from R11: 2-ahead staging pipeline (load(s+2) -> write(s+1 from packed
// regs) -> compute(s) -> pack(s+2) -> barrier); P in registers (swapped QK^T,
// lane holds the 16x16x16 A-frag); V swz ^((d&15)<<3) (odd rows as 2xb64);
// K swz ^(c&7)<<4; LDS 32KB dbuf.
// Block = 128 rows (4 waves x 32 rows), grid = 32 bh x 16 row-blocks = 512.
// 64-col segments, A = R:
//   s0..7 : summary pairs [256s+96,+128) u [256s+224,+256)       no mask
//   s8    : local [128A, +64)                                     mask a_row==A
//   s9    : local [128A+64,+96) (32) + checkpoints {128k,k=1..15}+pad (16), nn=3
//   s10/11: special block A-1 (R > 0 only); wave 0 computes.
// Coverage verified per-row (col 128A masked in checkpoint tile, unmasked in s8;
// col 128(A-1) masked in checkpoint tile for special row, unmasked in s10).

namespace {

constexpr int kS = 2048, kD = 64;

typedef __attribute__((ext_vector_type(8))) short short8;
typedef __attribute__((ext_vector_type(4))) short short4b;
typedef __attribute__((ext_vector_type(4))) float f32x4;
typedef __attribute__((ext_vector_type(4))) unsigned int u32x4;
typedef __attribute__((ext_vector_type(2))) unsigned int u32x2;

__device__ __forceinline__ unsigned f2bf(float f) {           // RNE (Q only)
    unsigned u = __builtin_bit_cast(unsigned, f);
    u += 0x7fffu + ((u >> 16) & 1u);
    return u >> 16;
}
__device__ __forceinline__ unsigned pk2(float a, float b) {   // RNE pair
    return f2bf(a) | (f2bf(b) << 16);
}
__device__ __forceinline__ unsigned pkt(float a, float b) {   // truncating pair: 1 v_perm
    return __builtin_amdgcn_perm(__builtin_bit_cast(unsigned, b),
                                 __builtin_bit_cast(unsigned, a), 0x07060302u);
}

#if __has_builtin(__builtin_amdgcn_mfma_f32_16x16x16bf16_1k)
__device__ __forceinline__ f32x4 mfma16(short4b a, short4b b, f32x4 c) {
    return __builtin_amdgcn_mfma_f32_16x16x16bf16_1k(a, b, c, 0, 0, 0);
}
#else
__device__ __forceinline__ f32x4 mfma16(short4b a, short4b b, f32x4 c) {
    asm volatile("v_mfma_f32_16x16x16_bf16 %0, %1, %2, %0"
                 : "+v"(c) : "v"(a), "v"(b));
    return c;
}
#endif

__device__ __forceinline__ int seglen(int s) { return s == 9 ? 48 : (s == 11 ? 32 : 64); }

__device__ __forceinline__ int colOf(int s, int p, int A) {
    if (s < 8)  return 256 * s + (p < 32 ? 96 + p : 192 + p);
    if (s == 8) return 128 * A + p;
    if (s == 9) {
        if (p < 32) return 128 * A + 64 + p;
        const int k = p - 31;                 // 1..16
        return k < 16 ? 128 * k : 2047;       // p=47 pad (always masked)
    }
    if (s == 10) return 128 * (A - 1) + p;
    return 128 * (A - 1) + 64 + p;            // s==11
}
__device__ __forceinline__ bool maskOf(int s, int p, int a_row, int A) {
    if (s < 8)  return true;
    if (s == 8) return a_row == A;
    if (s == 9) return p < 32 ? (a_row == A) : (p < 47 && a_row != (p - 31));
    return a_row == A - 1;                    // s==10/11
}

__global__ __launch_bounds__(256) void sparse_attn10(
    const float* __restrict__ Q, const float* __restrict__ K,
    const float* __restrict__ V, float* __restrict__ Out)
{
    // [0,16K):   K dbuf 2 x 8KB  [c(64)][d(64)] bf16, swz byte ^= (c&7)<<4
    // [16K,32K): V^T dbuf 2 x 8KB [d(64)][c(64)] bf16, swz byte ^= (d&15)<<3
    __shared__ __align__(16) unsigned char lds[32768];

    const int tid = threadIdx.x;
    const int wv = tid >> 6;
    const int l = tid & 63, g = l >> 4, lm = l & 15;
    const int bh = blockIdx.x >> 4, R = blockIdx.x & 15;
    const int A = R;
    const int rowbase = R * 128 + wv * 32;      // wave owns 32 rows (2 tiles)
    const bool spec = (R > 0);
    const int nseg = spec ? 12 : 10;

    const float* Qb = Q + (size_t)bh * kS * kD;
    const float* Kb = K + (size_t)bh * kS * kD;
    const float* Vb = V + (size_t)bh * kS * kD;

    // Q fragments, tile m (rows rowbase+16m+q, q=lm): B-operand of swapped QK
    short8 qa[2][2];
#pragma unroll
    for (int m = 0; m < 2; ++m)
#pragma unroll
    for (int kk = 0; kk < 2; ++kk) {
        const float* qp = Qb + (size_t)(rowbase + 16*m + lm) * kD + kk*32 + g*8;
        float4 a = *(const float4*)qp;
        float4 b = *(const float4*)(qp + 4);
        u32x4 t;
        t.x = pk2(a.x*0.125f, a.y*0.125f);
        t.y = pk2(a.z*0.125f, a.w*0.125f);
        t.z = pk2(b.x*0.125f, b.y*0.125f);
        t.w = pk2(b.z*0.125f, b.w*0.125f);
        qa[m][kk] = __builtin_bit_cast(short8, t);
    }

    int aq[2];
#pragma unroll
    for (int m = 0; m < 2; ++m) {
        const int qrow = rowbase + 16*m + lm;
        aq[m] = (qrow >> 7) - (((qrow & 127) == 0 && qrow > 0) ? 1 : 0);
    }

    float mrun[2] = {-1e30f, -1e30f}, lpar[2] = {0.f, 0.f};
    f32x4 o[2][4];                       // O[tile m][q=4g+i][d=lm+16nv]
#pragma unroll
    for (int m = 0; m < 2; ++m)
#pragma unroll
    for (int nv = 0; nv < 4; ++nv) o[m][nv] = (f32x4){0.f,0.f,0.f,0.f};

    // pipeline registers
    float4 kreg[4];                      // fp32 in flight (intra-interval)
    float2 vreg[8];
    u32x4  kp0, kp1;                     // packed bf16, held ACROSS the barrier
    u32x4  vp0;
    u32x2  vp1a, vp1b;

    const int kc  = tid >> 2,  kq4 = tid & 3;              // K staging coords
    const int vc0 = (tid >> 5) * 8, vd0 = (tid & 31) * 2;  // V staging coords

    auto stage_load = [&](int s) {       // issue global loads only
        const int len = seglen(s);
        if (kc < len) {
            const float* kp = Kb + (size_t)colOf(s, kc, A) * kD + kq4*16;
            kreg[0] = *(const float4*)(kp);
            kreg[1] = *(const float4*)(kp + 4);
            kreg[2] = *(const float4*)(kp + 8);
            kreg[3] = *(const float4*)(kp + 12);
        }
        if (vc0 < len) {
#pragma unroll
            for (int j = 0; j < 8; ++j)
                vreg[j] = *(const float2*)(Vb + (size_t)colOf(s, vc0 + j, A) * kD + vd0);
        }
    };

    auto stage_pack = [&](int s) {       // vmcnt waits land here (covered by compute)
        const int len = seglen(s);
        if (kc < len) {
            kp0.x = pkt(kreg[0].x,kreg[0].y); kp0.y = pkt(kreg[0].z,kreg[0].w);
            kp0.z = pkt(kreg[1].x,kreg[1].y); kp0.w = pkt(kreg[1].z,kreg[1].w);
            kp1.x = pkt(kreg[2].x,kreg[2].y); kp1.y = pkt(kreg[2].z,kreg[2].w);
            kp1.z = pkt(kreg[3].x,kreg[3].y); kp1.w = pkt(kreg[3].z,kreg[3].w);
        }
        if (vc0 < len) {
            vp0.x = pkt(vreg[0].x,vreg[1].x); vp0.y = pkt(vreg[2].x,vreg[3].x);
            vp0.z = pkt(vreg[4].x,vreg[5].x); vp0.w = pkt(vreg[6].x,vreg[7].x);
            vp1a.x = pkt(vreg[0].y,vreg[1].y); vp1a.y = pkt(vreg[2].y,vreg[3].y);
            vp1b.x = pkt(vreg[4].y,vreg[5].y); vp1b.y = pkt(vreg[6].y,vreg[7].y);
        }
    };

    auto stage_write = [&](int s, int buf) {   // LDS writes from packed regs only
        unsigned char* ksb = lds + buf * 8192;
        unsigned char* vsb = lds + 16384 + buf * 8192;
        const int len = seglen(s);
        if (kc < len) {
            const unsigned b  = (unsigned)(kc*128 + kq4*32);
            const unsigned sw = ((unsigned)(kc & 7)) << 4;
            *(u32x4*)(ksb + (b ^ sw))        = kp0;
            *(u32x4*)(ksb + ((b ^ sw) ^ 16)) = kp1;
        }
        if (vc0 < len) {
            // even row vd0: swz multiple of 16 -> contiguous b128 is exact
            const unsigned swe = ((unsigned)(vd0 & 15)) << 3;
            *(u32x4*)(vsb + ((unsigned)(vd0*128 + vc0*2) ^ swe)) = vp0;
            // odd row vd0+1: swz has bit 3 -> two b64 chunks (XOR exact at 8B)
            const unsigned swo = ((unsigned)((vd0 + 1) & 15)) << 3;
            *(u32x2*)(vsb + ((unsigned)((vd0+1)*128 + vc0*2)     ^ swo)) = vp1a;
            *(u32x2*)(vsb + ((unsigned)((vd0+1)*128 + vc0*2 + 8) ^ swo)) = vp1b;
        }
    };

    auto compute = [&](int s, int buf) {
        if (s >= 10 && wv != 0) return;      // special block: only wave 0's rows
        const int nn = (s == 9) ? 3 : ((s == 11) ? 2 : 4);
        const unsigned char* ksb = lds + buf * 8192;
        const unsigned char* vsb = lds + 16384 + buf * 8192;

        // S^T tiles: sf[m][n][i] = S[q=lm, tile m][c = 16n + 4g + i]
        f32x4 sf[2][4];
#pragma unroll
        for (int m = 0; m < 2; ++m)
#pragma unroll
        for (int n = 0; n < 4; ++n) sf[m][n] = (f32x4){0.f,0.f,0.f,0.f};

        __builtin_amdgcn_s_setprio(1);
#pragma unroll
        for (int n = 0; n < 4; ++n) if (n < nn) {
            const int c = lm + 16*n;         // K-fragment row (A-operand)
#pragma unroll
            for (int kk = 0; kk < 2; ++kk) {
                const unsigned byte = (unsigned)(c*128 + kk*64 + g*16) ^ (((unsigned)(c & 7)) << 4);
                const short8 kf = *(const short8*)(ksb + byte);   // shared by both tiles
                sf[0][n] = __builtin_amdgcn_mfma_f32_16x16x32_bf16(kf, qa[0][kk], sf[0][n], 0, 0, 0);
                sf[1][n] = __builtin_amdgcn_mfma_f32_16x16x32_bf16(kf, qa[1][kk], sf[1][n], 0, 0, 0);
            }
        }
        __builtin_amdgcn_s_setprio(0);

        if (s >= 8) {                        // mask: per lane, q-row = lm of tile m
#pragma unroll
            for (int m = 0; m < 2; ++m)
#pragma unroll
            for (int n = 0; n < 4; ++n) if (n < nn) {
#pragma unroll
                for (int i = 0; i < 4; ++i) {
                    const int c = 16*n + g*4 + i;
                    if (!maskOf(s, c, aq[m], A)) sf[m][n][i] = -1e30f;
                }
            }
        }

        // row max per tile: in-lane tree + 2 cross-g shfls; defer-max (THR=8)
        float tt[2]; bool need = false;
#pragma unroll
        for (int m = 0; m < 2; ++m) {
            float t = -1e30f;
#pragma unroll
            for (int n = 0; n < 4; ++n) if (n < nn)
                t = fmaxf(t, fmaxf(fmaxf(sf[m][n][0], sf[m][n][1]), fmaxf(sf[m][n][2], sf[m][n][3])));
            t = fmaxf(t, __shfl_xor(t, 16));
            t = fmaxf(t, __shfl_xor(t, 32));
            tt[m] = t;
            need = need || (t > mrun[m] + 8.f);
        }
        if (__any(need)) {
#pragma unroll
            for (int m = 0; m < 2; ++m) {
                const float nm = fmaxf(mrun[m], tt[m]);
                const float al = __expf(mrun[m] - nm);
                mrun[m] = nm; lpar[m] *= al;
#pragma unroll
                for (int i = 0; i < 4; ++i) {   // redistribute al to C-layout rows
                    const float ali = __shfl(al, (g*4 + i) + 16*g);
#pragma unroll
                    for (int nv = 0; nv < 4; ++nv) o[m][nv][i] *= ali;
                }
            }
        }

        // exp + pack: pa[m][n] IS the 16x16x16 A-frag (row=q=lm, k=4g+i)
        u32x2 pa[2][4];
#pragma unroll
        for (int m = 0; m < 2; ++m) {
            float psum = 0.f;
#pragma unroll
            for (int n = 0; n < 4; ++n) if (n < nn) {
                const float p0 = __expf(sf[m][n][0] - mrun[m]);
                const float p1 = __expf(sf[m][n][1] - mrun[m]);
                const float p2 = __expf(sf[m][n][2] - mrun[m]);
                const float p3 = __expf(sf[m][n][3] - mrun[m]);
                psum += (p0 + p1) + (p2 + p3);
                pa[m][n].x = pkt(p0, p1);
                pa[m][n].y = pkt(p2, p3);
            }
            lpar[m] += psum;
        }

        // PV: o[m][nv] += P_n * V_n, K=16 per tile; vb shared by both tiles
        __builtin_amdgcn_s_setprio(1);
#pragma unroll
        for (int nv = 0; nv < 4; ++nv) {
            const int d = lm + 16*nv;
            const unsigned dsw = ((unsigned)(d & 15)) << 3;
#pragma unroll
            for (int n = 0; n < 4; ++n) if (n < nn) {
                const unsigned byte = ((unsigned)(d*128 + 32*n + 8*g)) ^ dsw;
                const short4b vb = *(const short4b*)(vsb + byte);
                o[0][nv] = mfma16(__builtin_bit_cast(short4b, pa[0][n]), vb, o[0][nv]);
                o[1][nv] = mfma16(__builtin_bit_cast(short4b, pa[1][n]), vb, o[1][nv]);
            }
        }
        __builtin_amdgcn_s_setprio(0);
    };

    // prologue: seg 0 fully staged; seg 1 loaded+packed (held in regs)
    stage_load(0); stage_pack(0); stage_write(0, 0);
    stage_load(1); stage_pack(1);
    __syncthreads();

    for (int s = 0; s < nseg; ++s) {
        if (s + 2 < nseg) stage_load(s + 2);                // issue 2 ahead
        if (s + 1 < nseg) stage_write(s + 1, (s + 1) & 1);  // from packed regs
        compute(s, s & 1);                                  // covers load latency
        if (s + 2 < nseg) stage_pack(s + 2);                // vmcnt wait ~free here
        __syncthreads();
    }

    // epilogue per tile: row sum, redistribute 1/l to C-layout rows, store fp32
#pragma unroll
    for (int m = 0; m < 2; ++m) {
        float v = lpar[m];
        v += __shfl_xor(v, 16);
        v += __shfl_xor(v, 32);
        const float linv = 1.f / v;
#pragma unroll
        for (int i = 0; i < 4; ++i) {
            const float inv = __shfl(linv, (g*4 + i) + 16*g);
            float* op = Out + ((size_t)bh * kS + rowbase + 16*m + g*4 + i) * kD + lm;
#pragma unroll
            for (int nv = 0; nv < 4; ++nv)
                op[16*nv] = o[m][nv][i] * inv;
        }
    }
}

} // namespace

extern "C" void kernel_launch(void* const* d_in, const int* in_sizes, int n_in,
                              void* d_out, int out_size, void* d_ws, size_t ws_size,
                              hipStream_t stream) {
    const float* q = (const float*)d_in[0];
    const float* k = (const float*)d_in[1];
    const float* v = (const float*)d_in[2];
    // d_in[3] (mask) is a pure function of (S,STRIDE,EXPR) reproduced in-kernel.
    float* out = (float*)d_out;
    dim3 grid(512), block(256);
    hipLaunchKernelGGL(sparse_attn10, grid, block, 0, stream, q, k, v, out);
}

// Round 13
// 49.587 us; speedup vs baseline: 1.5545x; 1.5545x over previous
//
#include <hip/hip_runtime.h>
#include <math.h>

// SparseMultiheadAttention B=2,H=16,S=2048,DH=64, STRIDE=128, EXPR=32, bidirectional.
// Mask factorization (HW-validated rounds 0-2):
//   allowed(i,c) = (c&127)>=96 | ((c&127)==0 && c>0) | ((c>>7)==a(i))
//   a(i) = (i>>7) - ((i&127)==0 && i>0)
// R13 = R11 structure with 8-wave 512-thread blocks (128 rows, grid 512) and
// TWO 64-col sub-segments per barrier interval, computed SEQUENTIALLY so the
// per-wave register state stays R11-sized (R12's 2-tiles-per-wave doubled live
// VGPRs -> 152 regs, occupancy collapse; reverted). Per-CU barrier events drop
// 42 -> 11; K/V staged once per 128 rows (FETCH halves); per-wave work as R11.
// Kept: 2-ahead interval pipeline (load(I+2) -> write(I+1 from packed regs) ->
// compute(I) -> pack(I+2) -> barrier); P in registers (swapped QK^T, lane owns
// the 16x16x16 A-frag); V swz ^((d&15)<<3) (odd rows as 2xb64); K swz ^(c&7)<<4.
// LDS 64KB = 2 bufs x (K 2x8K + V 2x8K) -> 2 blocks/CU.
// Sub-segments (A = R, block rows [128R,128R+128)):
//   s0..7 : summary pairs [256s+96,+128) u [256s+224,+256)       no mask
//   s8    : local [128A, +64)                                     mask a_row==A
//   s9    : local [128A+64,+96) (32) + checkpoints {128k,k=1..15}+pad (16), nn=3
//   s10/11: special block A-1 (R > 0 only); wave 0 computes (row 128R only).
// Intervals: I = {2I, 2I+1}; nI = spec ? 6 : 5 (pairs always complete).
// Coverage verified per-row (col 128A masked in checkpoint tile, unmasked in s8;
// col 128(A-1) masked in checkpoint tile for special row, unmasked in s10).

namespace {

constexpr int kS = 2048, kD = 64;

typedef __attribute__((ext_vector_type(8))) short short8;
typedef __attribute__((ext_vector_type(4))) short short4b;
typedef __attribute__((ext_vector_type(4))) float f32x4;
typedef __attribute__((ext_vector_type(4))) unsigned int u32x4;
typedef __attribute__((ext_vector_type(2))) unsigned int u32x2;

__device__ __forceinline__ unsigned f2bf(float f) {           // RNE (Q only)
    unsigned u = __builtin_bit_cast(unsigned, f);
    u += 0x7fffu + ((u >> 16) & 1u);
    return u >> 16;
}
__device__ __forceinline__ unsigned pk2(float a, float b) {   // RNE pair
    return f2bf(a) | (f2bf(b) << 16);
}
__device__ __forceinline__ unsigned pkt(float a, float b) {   // truncating pair: 1 v_perm
    return __builtin_amdgcn_perm(__builtin_bit_cast(unsigned, b),
                                 __builtin_bit_cast(unsigned, a), 0x07060302u);
}

#if __has_builtin(__builtin_amdgcn_mfma_f32_16x16x16bf16_1k)
__device__ __forceinline__ f32x4 mfma16(short4b a, short4b b, f32x4 c) {
    return __builtin_amdgcn_mfma_f32_16x16x16bf16_1k(a, b, c, 0, 0, 0);
}
#else
__device__ __forceinline__ f32x4 mfma16(short4b a, short4b b, f32x4 c) {
    asm volatile("v_mfma_f32_16x16x16_bf16 %0, %1, %2, %0"
                 : "+v"(c) : "v"(a), "v"(b));
    return c;
}
#endif

__device__ __forceinline__ int seglen(int s) { return s == 9 ? 48 : (s == 11 ? 32 : 64); }

__device__ __forceinline__ int colOf(int s, int p, int A) {
    if (s < 8)  return 256 * s + (p < 32 ? 96 + p : 192 + p);
    if (s == 8) return 128 * A + p;
    if (s == 9) {
        if (p < 32) return 128 * A + 64 + p;
        const int k = p - 31;                 // 1..16
        return k < 16 ? 128 * k : 2047;       // p=47 pad (always masked)
    }
    if (s == 10) return 128 * (A - 1) + p;
    return 128 * (A - 1) + 64 + p;            // s==11
}
__device__ __forceinline__ bool maskOf(int s, int p, int a_row, int A) {
    if (s < 8)  return true;
    if (s == 8) return a_row == A;
    if (s == 9) return p < 32 ? (a_row == A) : (p < 47 && a_row != (p - 31));
    return a_row == A - 1;                    // s==10/11
}

__global__ __launch_bounds__(512) void sparse_attn11(
    const float* __restrict__ Q, const float* __restrict__ K,
    const float* __restrict__ V, float* __restrict__ Out)
{
    // buf b at b*32768: K sub-seg u at +u*8192 (swz ^(c&7)<<4),
    //                   V sub-seg u at +16384+u*8192 (swz ^((d&15)<<3))
    __shared__ __align__(16) unsigned char lds[65536];

    const int tid = threadIdx.x;
    const int wv = tid >> 6;                     // 0..7
    const int l = tid & 63, g = l >> 4, lm = l & 15;
    const int bh = blockIdx.x >> 4, R = blockIdx.x & 15;
    const int A = R;
    const int rowbase = R * 128 + wv * 16;       // wave owns 16 rows (R11-sized)
    const bool spec = (R > 0);
    const int nsub = spec ? 12 : 10;
    const int nI   = spec ? 6 : 5;               // pairs always complete

    const float* Qb = Q + (size_t)bh * kS * kD;
    const float* Kb = K + (size_t)bh * kS * kD;
    const float* Vb = V + (size_t)bh * kS * kD;

    // Q fragment (mfma B-operand in swapped QK: col=q=lm, k=d=g*8+j+32kk)
    short8 qa[2];
#pragma unroll
    for (int kk = 0; kk < 2; ++kk) {
        const float* qp = Qb + (size_t)(rowbase + lm) * kD + kk*32 + g*8;
        float4 a = *(const float4*)qp;
        float4 b = *(const float4*)(qp + 4);
        u32x4 t;
        t.x = pk2(a.x*0.125f, a.y*0.125f);
        t.y = pk2(a.z*0.125f, a.w*0.125f);
        t.z = pk2(b.x*0.125f, b.y*0.125f);
        t.w = pk2(b.z*0.125f, b.w*0.125f);
        qa[kk] = __builtin_bit_cast(short8, t);
    }

    // a-value for this lane's q-row (q = rowbase + lm)
    const int qrow = rowbase + lm;
    const int aq = (qrow >> 7) - (((qrow & 127) == 0 && qrow > 0) ? 1 : 0);

    float mrun = -1e30f, lpar = 0.f;   // scalars: softmax state for q = lm
    f32x4 o[4];                         // O[q=4g+i][d=lm+16nv]
#pragma unroll
    for (int nv = 0; nv < 4; ++nv) o[nv] = (f32x4){0.f,0.f,0.f,0.f};

    // staging: thread-group (tid>>8) owns sub-seg u = group of each interval;
    // per-thread pattern identical to R11 (12 loads, pack, 5 LDS writes)
    const int group = tid >> 8;                  // 0 or 1
    const int tid_g = tid & 255;
    const int kc  = tid_g >> 2,  kq4 = tid_g & 3;
    const int vc0 = (tid_g >> 5) * 8, vd0 = (tid_g & 31) * 2;

    float4 kreg[4];                      // fp32 in flight (intra-interval)
    float2 vreg[8];
    u32x4  kp0, kp1;                     // packed bf16, held ACROSS the barrier
    u32x4  vp0;
    u32x2  vp1a, vp1b;

    auto stage_load = [&](int I) {       // issue global loads only
        const int s = 2*I + group;
        if (s >= nsub) return;
        const int len = seglen(s);
        if (kc < len) {
            const float* kp = Kb + (size_t)colOf(s, kc, A) * kD + kq4*16;
            kreg[0] = *(const float4*)(kp);
            kreg[1] = *(const float4*)(kp + 4);
            kreg[2] = *(const float4*)(kp + 8);
            kreg[3] = *(const float4*)(kp + 12);
        }
        if (vc0 < len) {
#pragma unroll
            for (int j = 0; j < 8; ++j)
                vreg[j] = *(const float2*)(Vb + (size_t)colOf(s, vc0 + j, A) * kD + vd0);
        }
    };

    auto stage_pack = [&](int I) {       // vmcnt waits land here (covered by compute)
        const int s = 2*I + group;
        if (s >= nsub) return;
        const int len = seglen(s);
        if (kc < len) {
            kp0.x = pkt(kreg[0].x,kreg[0].y); kp0.y = pkt(kreg[0].z,kreg[0].w);
            kp0.z = pkt(kreg[1].x,kreg[1].y); kp0.w = pkt(kreg[1].z,kreg[1].w);
            kp1.x = pkt(kreg[2].x,kreg[2].y); kp1.y = pkt(kreg[2].z,kreg[2].w);
            kp1.z = pkt(kreg[3].x,kreg[3].y); kp1.w = pkt(kreg[3].z,kreg[3].w);
        }
        if (vc0 < len) {
            vp0.x = pkt(vreg[0].x,vreg[1].x); vp0.y = pkt(vreg[2].x,vreg[3].x);
            vp0.z = pkt(vreg[4].x,vreg[5].x); vp0.w = pkt(vreg[6].x,vreg[7].x);
            vp1a.x = pkt(vreg[0].y,vreg[1].y); vp1a.y = pkt(vreg[2].y,vreg[3].y);
            vp1b.x = pkt(vreg[4].y,vreg[5].y); vp1b.y = pkt(vreg[6].y,vreg[7].y);
        }
    };

    auto stage_write = [&](int I, int buf) {   // LDS writes from packed regs only
        const int s = 2*I + group;
        if (s >= nsub) return;
        unsigned char* ksb = lds + buf * 32768 + group * 8192;
        unsigned char* vsb = lds + buf * 32768 + 16384 + group * 8192;
        const int len = seglen(s);
        if (kc < len) {
            const unsigned b  = (unsigned)(kc*128 + kq4*32);
            const unsigned sw = ((unsigned)(kc & 7)) << 4;
            *(u32x4*)(ksb + (b ^ sw))        = kp0;
            *(u32x4*)(ksb + ((b ^ sw) ^ 16)) = kp1;
        }
        if (vc0 < len) {
            // even row vd0: swz multiple of 16 -> contiguous b128 is exact
            const unsigned swe = ((unsigned)(vd0 & 15)) << 3;
            *(u32x4*)(vsb + ((unsigned)(vd0*128 + vc0*2) ^ swe)) = vp0;
            // odd row vd0+1: swz has bit 3 -> two b64 chunks (XOR exact at 8B)
            const unsigned swo = ((unsigned)((vd0 + 1) & 15)) << 3;
            *(u32x2*)(vsb + ((unsigned)((vd0+1)*128 + vc0*2)     ^ swo)) = vp1a;
            *(u32x2*)(vsb + ((unsigned)((vd0+1)*128 + vc0*2 + 8) ^ swo)) = vp1b;
        }
    };

    auto compute = [&](int I, int buf) {
        // two sub-segments back-to-back; per-sub-seg state dies before the next
        // (keeps live VGPRs at R11 levels -- the R12 lesson)
#pragma unroll
        for (int u = 0; u < 2; ++u) {
            const int s = 2*I + u;
            if (s >= nsub) continue;
            if (s >= 10 && wv != 0) continue;    // special: only wave 0's rows
            const int nn = (s == 9) ? 3 : ((s == 11) ? 2 : 4);
            const unsigned char* ksb = lds + buf * 32768 + u * 8192;
            const unsigned char* vsb = lds + buf * 32768 + 16384 + u * 8192;

            // S^T tiles: sf[n][i] = S[q=lm][c = 16n + 4g + i]
            f32x4 sf[4];
#pragma unroll
            for (int n = 0; n < 4; ++n) sf[n] = (f32x4){0.f,0.f,0.f,0.f};

            __builtin_amdgcn_s_setprio(1);
#pragma unroll
            for (int n = 0; n < 4; ++n) if (n < nn) {
                const int c = lm + 16*n;         // K-fragment row (A-operand)
#pragma unroll
                for (int kk = 0; kk < 2; ++kk) {
                    const unsigned byte = (unsigned)(c*128 + kk*64 + g*16) ^ (((unsigned)(c & 7)) << 4);
                    const short8 kf = *(const short8*)(ksb + byte);
                    sf[n] = __builtin_amdgcn_mfma_f32_16x16x32_bf16(kf, qa[kk], sf[n], 0, 0, 0);
                }
            }
            __builtin_amdgcn_s_setprio(0);

            if (s >= 8) {                        // mask: per lane, q-row = lm
#pragma unroll
                for (int n = 0; n < 4; ++n) if (n < nn) {
#pragma unroll
                    for (int i = 0; i < 4; ++i) {
                        const int c = 16*n + g*4 + i;
                        if (!maskOf(s, c, aq, A)) sf[n][i] = -1e30f;
                    }
                }
            }

            // row max: in-lane tree + 2 cross-g shfls; defer-max (THR=8)
            float t = -1e30f;
#pragma unroll
            for (int n = 0; n < 4; ++n) if (n < nn) {
                t = fmaxf(t, fmaxf(fmaxf(sf[n][0], sf[n][1]), fmaxf(sf[n][2], sf[n][3])));
            }
            t = fmaxf(t, __shfl_xor(t, 16));
            t = fmaxf(t, __shfl_xor(t, 32));
            const bool need = t > mrun + 8.f;
            if (__any(need)) {
                const float nm = fmaxf(mrun, t);
                const float al = __expf(mrun - nm);
                mrun = nm; lpar *= al;
#pragma unroll
                for (int i = 0; i < 4; ++i) {    // redistribute al to C-layout rows
                    const float ali = __shfl(al, (g*4 + i) + 16*g);
#pragma unroll
                    for (int nv = 0; nv < 4; ++nv) o[nv][i] *= ali;
                }
            }

            // exp + pack: pa[n] IS the 16x16x16 A-frag (row=q=lm, k=4g+i)
            u32x2 pa[4];
            float psum = 0.f;
#pragma unroll
            for (int n = 0; n < 4; ++n) if (n < nn) {
                const float p0 = __expf(sf[n][0] - mrun);
                const float p1 = __expf(sf[n][1] - mrun);
                const float p2 = __expf(sf[n][2] - mrun);
                const float p3 = __expf(sf[n][3] - mrun);
                psum += (p0 + p1) + (p2 + p3);
                pa[n].x = pkt(p0, p1);
                pa[n].y = pkt(p2, p3);
            }
            lpar += psum;

            // PV: o[nv] += P_n * V_n, K=16 per tile; V b64 reads conflict-free
            __builtin_amdgcn_s_setprio(1);
#pragma unroll
            for (int nv = 0; nv < 4; ++nv) {
                const int d = lm + 16*nv;
                const unsigned dsw = ((unsigned)(d & 15)) << 3;
#pragma unroll
                for (int n = 0; n < 4; ++n) if (n < nn) {
                    const unsigned byte = ((unsigned)(d*128 + 32*n + 8*g)) ^ dsw;
                    const short4b vb = *(const short4b*)(vsb + byte);
                    o[nv] = mfma16(__builtin_bit_cast(short4b, pa[n]), vb, o[nv]);
                }
            }
            __builtin_amdgcn_s_setprio(0);
        }
    };

    // prologue: interval 0 fully staged; interval 1 loaded+packed (in regs)
    stage_load(0); stage_pack(0); stage_write(0, 0);
    stage_load(1); stage_pack(1);
    __syncthreads();

    for (int I = 0; I < nI; ++I) {
        if (I + 2 < nI) stage_load(I + 2);                // issue 2 ahead
        if (I + 1 < nI) stage_write(I + 1, (I + 1) & 1);  // from packed regs
        compute(I, I & 1);                                // covers load latency
        if (I + 2 < nI) stage_pack(I + 2);                // vmcnt wait ~free here
        __syncthreads();
    }

    // epilogue: total row sum for q=lm, redistribute 1/l to C-layout rows, store
    float v = lpar;
    v += __shfl_xor(v, 16);
    v += __shfl_xor(v, 32);
    const float linv = 1.f / v;
#pragma unroll
    for (int i = 0; i < 4; ++i) {
        const float inv = __shfl(linv, (g*4 + i) + 16*g);
        float* op = Out + ((size_t)bh * kS + rowbase + g*4 + i) * kD + lm;
#pragma unroll
        for (int nv = 0; nv < 4; ++nv)
            op[16*nv] = o[nv][i] * inv;
    }
}

} // namespace

extern "C" void kernel_launch(void* const* d_in, const int* in_sizes, int n_in,
                              void* d_out, int out_size, void* d_ws, size_t ws_size,
                              hipStream_t stream) {
    const float* q = (const float*)d_in[0];
    const float* k = (const float*)d_in[1];
    const float* v = (const float*)d_in[2];
    // d_in[3] (mask) is a pure function of (S,STRIDE,EXPR) reproduced in-kernel.
    float* out = (float*)d_out;
    dim3 grid(512), block(512);
    hipLaunchKernelGGL(sparse_attn11, grid, block, 0, stream, q, k, v, out);
}